// Round 6
// baseline (332.978 us; speedup 1.0000x reference)
//
#include <hip/hip_runtime.h>
#include <cmath>

// DBRX router: logits = x[16384,6144] @ W[6144,16]; softmax; top-4; L1-normalize.
// Outputs flat: weights fp32[16384*16] | top_weights fp32[16384*4] | experts(as float)[16384*4]
//
// Phase 1 (partial): 4096 waves (KSLICES=16 x 256 token-tiles), 16 waves/CU.
//   lane = token; each lane streams its own row CONTIGUOUSLY (8 x float4 = one
//   128B-line-aligned 32-d group), depth-2 group pipeline in registers. No LDS.
//   W addresses depend only on blockIdx/threadIdx.y -> wave-uniform -> s_load
//   (SGPR operand in v_fma, zero vector-memory cost).
// Phase 2 (finish): reduce 16 partials/token, softmax, stable top-4, L1-norm.

namespace {
constexpr int TOKENS = 16384;
constexpr int DIM    = 6144;
constexpr int NE     = 16;
constexpr int TOPK   = 4;
constexpr int T_TILE = 64;
constexpr int GD     = 32;                    // d per group (128B per lane)
constexpr int TOPW_OFF = TOKENS * NE;
constexpr int EXP_OFF  = TOPW_OFF + TOKENS * TOPK;
}

__device__ __forceinline__ void fma16(float xs, const float4& w0, const float4& w1,
                                      const float4& w2, const float4& w3,
                                      float (&ac)[NE]) {
    ac[0]  = fmaf(xs, w0.x, ac[0]);  ac[1]  = fmaf(xs, w0.y, ac[1]);
    ac[2]  = fmaf(xs, w0.z, ac[2]);  ac[3]  = fmaf(xs, w0.w, ac[3]);
    ac[4]  = fmaf(xs, w1.x, ac[4]);  ac[5]  = fmaf(xs, w1.y, ac[5]);
    ac[6]  = fmaf(xs, w1.z, ac[6]);  ac[7]  = fmaf(xs, w1.w, ac[7]);
    ac[8]  = fmaf(xs, w2.x, ac[8]);  ac[9]  = fmaf(xs, w2.y, ac[9]);
    ac[10] = fmaf(xs, w2.z, ac[10]); ac[11] = fmaf(xs, w2.w, ac[11]);
    ac[12] = fmaf(xs, w3.x, ac[12]); ac[13] = fmaf(xs, w3.y, ac[13]);
    ac[14] = fmaf(xs, w3.z, ac[14]); ac[15] = fmaf(xs, w3.w, ac[15]);
}

__device__ __forceinline__ void load8(float4 (&dst)[8], const float* __restrict__ src) {
    #pragma unroll
    for (int i = 0; i < 8; ++i)
        dst[i] = *reinterpret_cast<const float4*>(src + 4 * i);
}

// one 32-d group: 8 quads; per quad 4 W rows x 16 experts from wave-uniform addrs
__device__ __forceinline__ void compute_group(const float4 (&buf)[8],
                                              const float* __restrict__ wbase,
                                              float (&acc)[NE]) {
    #pragma unroll
    for (int p = 0; p < 8; ++p) {
        const float* wp = wbase + p * 4 * NE;
        const float4 xq = buf[p];
        {
            const float4 a = *reinterpret_cast<const float4*>(wp + 0);
            const float4 b = *reinterpret_cast<const float4*>(wp + 4);
            const float4 c = *reinterpret_cast<const float4*>(wp + 8);
            const float4 d = *reinterpret_cast<const float4*>(wp + 12);
            fma16(xq.x, a, b, c, d, acc);
        }
        {
            const float4 a = *reinterpret_cast<const float4*>(wp + 16);
            const float4 b = *reinterpret_cast<const float4*>(wp + 20);
            const float4 c = *reinterpret_cast<const float4*>(wp + 24);
            const float4 d = *reinterpret_cast<const float4*>(wp + 28);
            fma16(xq.y, a, b, c, d, acc);
        }
        {
            const float4 a = *reinterpret_cast<const float4*>(wp + 32);
            const float4 b = *reinterpret_cast<const float4*>(wp + 36);
            const float4 c = *reinterpret_cast<const float4*>(wp + 40);
            const float4 d = *reinterpret_cast<const float4*>(wp + 44);
            fma16(xq.z, a, b, c, d, acc);
        }
        {
            const float4 a = *reinterpret_cast<const float4*>(wp + 48);
            const float4 b = *reinterpret_cast<const float4*>(wp + 52);
            const float4 c = *reinterpret_cast<const float4*>(wp + 56);
            const float4 d = *reinterpret_cast<const float4*>(wp + 60);
            fma16(xq.w, a, b, c, d, acc);
        }
    }
}

template <int KSLICES>
__global__ __launch_bounds__(256, 4) void router_partial_kernel(
    const float* __restrict__ x, const float* __restrict__ W,
    float* __restrict__ partial)
{
    constexpr int KS = DIM / KSLICES;         // d per wave
    constexpr int NG = KS / GD;               // groups (even for KSLICES in {8,16})

    const int lane = threadIdx.x;             // 0..63 = token within tile
    const int wid  = blockIdx.x * 4 + threadIdx.y;
    const int slice = wid >> 8;               // 0..KSLICES-1 (256 tiles per slice)
    const int tile  = wid & 255;              // 0..255
    const int d0    = slice * KS;             // wave-uniform (blockIdx/tid.y only)

    const float* xrow = x + (size_t)(tile * T_TILE + lane) * DIM + d0;

    float acc[NE];
    #pragma unroll
    for (int e = 0; e < NE; ++e) acc[e] = 0.f;

    float4 A[8], B[8];
    load8(A, xrow);
    load8(B, xrow + GD);

    #pragma unroll 1
    for (int g = 0; g < NG; g += 2) {
        compute_group(A, W + (d0 + g * GD) * NE, acc);
        if (g + 2 < NG) load8(A, xrow + (g + 2) * GD);
        compute_group(B, W + (d0 + (g + 1) * GD) * NE, acc);
        if (g + 3 < NG) load8(B, xrow + (g + 3) * GD);
    }

    // partial[slice][token][e] — 64 lanes x 64B contiguous
    float* p = partial + ((size_t)slice * TOKENS + tile * T_TILE + lane) * NE;
    #pragma unroll
    for (int q = 0; q < 4; ++q)
        *reinterpret_cast<float4*>(p + q * 4) =
            make_float4(acc[4 * q], acc[4 * q + 1], acc[4 * q + 2], acc[4 * q + 3]);
}

template <int KSLICES>
__global__ __launch_bounds__(256) void router_finish_kernel(
    const float* __restrict__ partial, float* __restrict__ out)
{
    const int t = blockIdx.x * 256 + threadIdx.x;   // one token per thread
    float l[NE];
    {
        const float4* p0 = reinterpret_cast<const float4*>(partial + (size_t)t * NE);
        float4 a0 = p0[0], a1 = p0[1], a2 = p0[2], a3 = p0[3];
        #pragma unroll
        for (int s = 1; s < KSLICES; ++s) {
            const float4* q = reinterpret_cast<const float4*>(
                partial + ((size_t)s * TOKENS + t) * NE);
            float4 b0 = q[0], b1 = q[1], b2 = q[2], b3 = q[3];
            a0.x += b0.x; a0.y += b0.y; a0.z += b0.z; a0.w += b0.w;
            a1.x += b1.x; a1.y += b1.y; a1.z += b1.z; a1.w += b1.w;
            a2.x += b2.x; a2.y += b2.y; a2.z += b2.z; a2.w += b2.w;
            a3.x += b3.x; a3.y += b3.y; a3.z += b3.z; a3.w += b3.w;
        }
        l[0]=a0.x; l[1]=a0.y; l[2]=a0.z; l[3]=a0.w;
        l[4]=a1.x; l[5]=a1.y; l[6]=a1.z; l[7]=a1.w;
        l[8]=a2.x; l[9]=a2.y; l[10]=a2.z; l[11]=a2.w;
        l[12]=a3.x; l[13]=a3.y; l[14]=a3.z; l[15]=a3.w;
    }
    // softmax (max-subtracted, like jax.nn.softmax)
    float mx = l[0];
    #pragma unroll
    for (int e = 1; e < NE; ++e) mx = fmaxf(mx, l[e]);
    float w[NE];
    float sum = 0.f;
    #pragma unroll
    for (int e = 0; e < NE; ++e) { w[e] = expf(l[e] - mx); sum += w[e]; }
    const float inv = 1.f / sum;
    #pragma unroll
    for (int e = 0; e < NE; ++e) w[e] *= inv;

    // stable top-4: strict '>' keeps lowest index on ties (matches jax.lax.top_k)
    int   idx[TOPK];
    float tw[TOPK];
    unsigned used = 0;
    #pragma unroll
    for (int k = 0; k < TOPK; ++k) {
        float best = -1.f;
        int   bi   = 0;
        #pragma unroll
        for (int e = 0; e < NE; ++e) {
            const bool avail = ((used >> e) & 1u) == 0u;
            if (avail && w[e] > best) { best = w[e]; bi = e; }
        }
        used |= (1u << bi);
        idx[k] = bi;
        tw[k]  = best;
    }
    const float s4 = tw[0] + tw[1] + tw[2] + tw[3];
    const float rinv = 1.f / s4;

    const int tt = t;
    float4* o0 = reinterpret_cast<float4*>(out + (size_t)tt * NE);
    o0[0] = make_float4(w[0], w[1], w[2], w[3]);
    o0[1] = make_float4(w[4], w[5], w[6], w[7]);
    o0[2] = make_float4(w[8], w[9], w[10], w[11]);
    o0[3] = make_float4(w[12], w[13], w[14], w[15]);
    *reinterpret_cast<float4*>(out + TOPW_OFF + (size_t)tt * TOPK) =
        make_float4(tw[0] * rinv, tw[1] * rinv, tw[2] * rinv, tw[3] * rinv);
    *reinterpret_cast<float4*>(out + EXP_OFF + (size_t)tt * TOPK) =
        make_float4((float)idx[0], (float)idx[1], (float)idx[2], (float)idx[3]);
}

template <int KSLICES>
static void launch_impl(const float* x, const float* W, float* out, float* ws,
                        hipStream_t stream)
{
    const int blocks = KSLICES * 64;          // waves = KSLICES*256; 4 waves/block
    router_partial_kernel<KSLICES><<<blocks, dim3(64, 4, 1), 0, stream>>>(x, W, ws);
    router_finish_kernel<KSLICES><<<TOKENS / 256, 256, 0, stream>>>(ws, out);
}

extern "C" void kernel_launch(void* const* d_in, const int* in_sizes, int n_in,
                              void* d_out, int out_size, void* d_ws, size_t ws_size,
                              hipStream_t stream) {
    const float* x = (const float*)d_in[0];
    const float* W = (const float*)d_in[1];
    float* out = (float*)d_out;
    float* ws  = (float*)d_ws;

    const size_t per_slice = (size_t)TOKENS * NE * sizeof(float);  // 1 MB
    if (ws_size >= 16 * per_slice) {
        launch_impl<16>(x, W, out, ws, stream);   // 1024 blocks, 16 waves/CU
    } else {
        launch_impl<8>(x, W, out, ws, stream);    // 512 blocks
    }
}